// Round 3
// baseline (73.703 us; speedup 1.0000x reference)
//
#include <hip/hip_runtime.h>

#define DIM 4096
#define BATCH 128
// K1 LDS strides (float2 units): addr = li0*K1S0 + i1*K1S1 + i2   (li0 in 0..3)
#define K1S0 274
#define K1S1 17
// K2 LDS strides (float2 units): addr = i0*K2S0 + li1*K2S1 + i2   (li1 in 0..3)
#define K2S0 69
#define K2S1 17

// One in-place contraction pass over a 1024-element (64-fiber) LDS state.
// 256 threads: fpair = t&31 selects 2 fibers {fpair, fpair+32}; r0 = 2*(t>>5)
// selects 2 gate rows. Gate rows live in registers (half-wave-uniform LDS
// broadcast). All fiber reads complete before the barrier => in-place safe.
__device__ __forceinline__ void contract_pass(float2* __restrict__ st,
                                              const float2 (*__restrict__ G)[16],
                                              const int t, const int BH,
                                              const int BK, const int STRIDE)
{
    const int fpair = t & 31;
    const int r0 = (t >> 5) << 1;
    float2 g0[16], g1[16];
#pragma unroll
    for (int j = 0; j < 16; ++j) {
        g0[j] = G[r0][j];
        g1[j] = G[r0 + 1][j];
    }
    float2 y[2][2];
#pragma unroll
    for (int fl = 0; fl < 2; ++fl) {
        const int f = fpair + (fl << 5);
        const int base = (f >> 4) * BH + (f & 15) * BK;
        float2 x[16];
#pragma unroll
        for (int j = 0; j < 16; ++j) x[j] = st[base + j * STRIDE];
        float ar0 = 0.f, ai0 = 0.f, ar1 = 0.f, ai1 = 0.f;
#pragma unroll
        for (int j = 0; j < 16; ++j) {
            ar0 = fmaf(g0[j].x,  x[j].x, ar0);
            ar0 = fmaf(-g0[j].y, x[j].y, ar0);
            ai0 = fmaf(g0[j].x,  x[j].y, ai0);
            ai0 = fmaf(g0[j].y,  x[j].x, ai0);
            ar1 = fmaf(g1[j].x,  x[j].x, ar1);
            ar1 = fmaf(-g1[j].y, x[j].y, ar1);
            ai1 = fmaf(g1[j].x,  x[j].y, ai1);
            ai1 = fmaf(g1[j].y,  x[j].x, ai1);
        }
        y[fl][0] = make_float2(ar0, ai0);
        y[fl][1] = make_float2(ar1, ai1);
    }
    __syncthreads();
#pragma unroll
    for (int fl = 0; fl < 2; ++fl) {
        const int f = fpair + (fl << 5);
        const int base = (f >> 4) * BH + (f & 15) * BK;
        st[base + r0 * STRIDE]       = y[fl][0];
        st[base + (r0 + 1) * STRIDE] = y[fl][1];
    }
    __syncthreads();
}

// K1: block = (batch b, i0-quarter q). Applies U2 (contract i2) then U1
// (contract i1) to the 1024-element slab i0 in [4q,4q+4). Writes interleaved
// float2 to ws in natural [b][4096] layout.
__global__ __launch_bounds__(256)
void ulayer_k1(const float* __restrict__ thetas,
               const float* __restrict__ evecs,
               const float* __restrict__ evals,
               const float* __restrict__ sre,
               const float* __restrict__ sim,
               float2* __restrict__ ws)
{
    __shared__ float  sV[256];
    __shared__ float  sC[48];
    __shared__ float  sS[48];
    __shared__ float2 sG[3][16][16];
    __shared__ float2 st[4 * K1S0];

    const int t = threadIdx.x;
    const int b = blockIdx.x >> 2;
    const int q = blockIdx.x & 3;

    sV[t] = evecs[t];
    if (t < 48) {
        const int g = t >> 4, k = t & 15;
        float sn, cs;
        sincosf(thetas[g] * evals[k], &sn, &cs);
        sC[t] = cs;
        sS[t] = sn;
    }

    // early global loads: this block's contiguous 1024-float slab, re + im
    const float4 re4 = *(const float4*)(sre + (size_t)b * DIM + q * 1024 + t * 4);
    const float4 im4 = *(const float4*)(sim + (size_t)b * DIM + q * 1024 + t * 4);

    __syncthreads();

    // build gates U1, U2: U[i,j] = sum_k V[i,k]V[j,k] * (cos - i sin)
#pragma unroll
    for (int rep = 0; rep < 2; ++rep) {
        const int e = t + (rep << 8);          // 0..511
        const int g = 1 + (e >> 8);            // 1 or 2
        const int i = (e >> 4) & 15;
        const int j = e & 15;
        float gr = 0.f, gi = 0.f;
#pragma unroll
        for (int k = 0; k < 16; ++k) {
            const float vv = sV[i * 16 + k] * sV[j * 16 + k];
            gr = fmaf(vv,  sC[(g << 4) + k], gr);
            gi = fmaf(vv, -sS[(g << 4) + k], gi);
        }
        sG[g][i][j] = make_float2(gr, gi);
    }

    // scatter state into padded LDS
    const int e0  = t << 2;
    const int li0 = e0 >> 8;
    const int i1  = (e0 >> 4) & 15;
    const int i2  = e0 & 15;                   // in {0,4,8,12}
    const int sbase = li0 * K1S0 + i1 * K1S1 + i2;
    st[sbase + 0] = make_float2(re4.x, im4.x);
    st[sbase + 1] = make_float2(re4.y, im4.y);
    st[sbase + 2] = make_float2(re4.z, im4.z);
    st[sbase + 3] = make_float2(re4.w, im4.w);
    __syncthreads();

    // U2: fibers (li0,i1), stride 1.   U1: fibers (li0,i2), stride 17.
    contract_pass(st, sG[2], t, K1S0, K1S1, 1);
    contract_pass(st, sG[1], t, K1S0, 1, K1S1);

    // write interleaved float2 slab to ws (coalesced, 32B/thread)
    const float2 a0 = st[sbase + 0];
    const float2 a1 = st[sbase + 1];
    const float2 a2 = st[sbase + 2];
    const float2 a3 = st[sbase + 3];
    float4* wp = (float4*)(ws + (size_t)b * DIM + q * 1024 + e0);
    wp[0] = make_float4(a0.x, a0.y, a1.x, a1.y);
    wp[1] = make_float4(a2.x, a2.y, a3.x, a3.y);
}

// K2: block = (batch b, i1-quarter p). Applies U0 (contract i0) to the 1024
// elements (all i0, i1 in [4p,4p+4), all i2). Writes final [2][B][DIM] output.
__global__ __launch_bounds__(256)
void ulayer_k2(const float* __restrict__ thetas,
               const float* __restrict__ evecs,
               const float* __restrict__ evals,
               const float2* __restrict__ ws,
               float* __restrict__ out)
{
    __shared__ float  sV[256];
    __shared__ float  sC[16];
    __shared__ float  sS[16];
    __shared__ float2 sG0[16][16];
    __shared__ float2 st[16 * K2S0];

    const int t = threadIdx.x;
    const int b = blockIdx.x >> 2;
    const int p = blockIdx.x & 3;

    sV[t] = evecs[t];
    if (t < 16) {
        float sn, cs;
        sincosf(thetas[0] * evals[t], &sn, &cs);
        sC[t] = cs;
        sS[t] = sn;
    }

    // early global loads: per i0, the 64 contiguous float2 for this i1-quarter
    const int i0 = t >> 4;
    const int r0 = (t & 15) << 2;              // 0..60, step 4
    const float2* wrow = ws + (size_t)b * DIM + i0 * 256 + p * 64 + r0;
    const float4 w0 = *(const float4*)(wrow);
    const float4 w1 = *(const float4*)(wrow + 2);

    __syncthreads();

    // build gate U0
    {
        const int i = t >> 4;
        const int j = t & 15;
        float gr = 0.f, gi = 0.f;
#pragma unroll
        for (int k = 0; k < 16; ++k) {
            const float vv = sV[i * 16 + k] * sV[j * 16 + k];
            gr = fmaf(vv,  sC[k], gr);
            gi = fmaf(vv, -sS[k], gi);
        }
        sG0[i][j] = make_float2(gr, gi);
    }

    // scatter into padded LDS: addr = i0*69 + li1*17 + i2
    const int li1 = r0 >> 4;
    const int i2  = r0 & 15;                   // in {0,4,8,12}
    const int sbase = i0 * K2S0 + li1 * K2S1 + i2;
    st[sbase + 0] = make_float2(w0.x, w0.y);
    st[sbase + 1] = make_float2(w0.z, w0.w);
    st[sbase + 2] = make_float2(w1.x, w1.y);
    st[sbase + 3] = make_float2(w1.z, w1.w);
    __syncthreads();

    // U0: fibers (li1,i2), stride 69 along i0
    contract_pass(st, sG0, t, K2S1, 1, K2S0);

    // write output planes [2][B][DIM]
    const float2 a0 = st[sbase + 0];
    const float2 a1 = st[sbase + 1];
    const float2 a2 = st[sbase + 2];
    const float2 a3 = st[sbase + 3];
    const size_t ooff = (size_t)b * DIM + i0 * 256 + p * 64 + r0;
    *(float4*)(out + ooff) = make_float4(a0.x, a1.x, a2.x, a3.x);
    *(float4*)(out + (size_t)BATCH * DIM + ooff) = make_float4(a0.y, a1.y, a2.y, a3.y);
}

extern "C" void kernel_launch(void* const* d_in, const int* in_sizes, int n_in,
                              void* d_out, int out_size, void* d_ws, size_t ws_size,
                              hipStream_t stream) {
    const float* thetas = (const float*)d_in[0];
    const float* evecs  = (const float*)d_in[1];
    const float* evals  = (const float*)d_in[2];
    const float* sre    = (const float*)d_in[3];
    const float* sim    = (const float*)d_in[4];
    float* out = (float*)d_out;
    float2* ws = (float2*)d_ws;

    ulayer_k1<<<BATCH * 4, 256, 0, stream>>>(thetas, evecs, evals, sre, sim, ws);
    ulayer_k2<<<BATCH * 4, 256, 0, stream>>>(thetas, evecs, evals, ws, out);
}

// Round 4
// 71.072 us; speedup vs baseline: 1.0370x; 1.0370x over previous
//
#include <hip/hip_runtime.h>

#define DIM 4096
#define BATCH 128
#define NT 1024
// padded float2 strides inside LDS state buffer: addr = i0*S0 + i1*S1 + i2
#define S1 17
#define S0 274

__global__ __launch_bounds__(NT)
void ulayer_kernel(const float* __restrict__ thetas,
                   const float* __restrict__ evecs,
                   const float* __restrict__ evals,
                   const float* __restrict__ sre,
                   const float* __restrict__ sim,
                   float* __restrict__ out)
{
    __shared__ float  sV[256];
    __shared__ float  sC[48];
    __shared__ float  sS[48];
    __shared__ float2 sG[3][16][16];
    __shared__ float2 st[16 * S0];   // 4384 float2 = 35072 B

    const int t = threadIdx.x;
    const int b = blockIdx.x;

    // stage V (threads 0..255) and per-(gate,eig) trig (threads 256..303)
    if (t < 256) sV[t] = evecs[t];
    else if (t < 304) {
        const int e = t - 256;
        float sn, cs;
        sincosf(thetas[e >> 4] * evals[e & 15], &sn, &cs);
        sC[e] = cs;
        sS[e] = sn;
    }

    // early global loads: 4 floats re + 4 im per thread, fully coalesced
    const float4 re4 = *(const float4*)(sre + (size_t)b * DIM + (t << 2));
    const float4 im4 = *(const float4*)(sim + (size_t)b * DIM + (t << 2));

    __syncthreads();

    // build the three 16x16 complex gates: U[i,j] = sum_k V[i,k]V[j,k]*(cos - i sin)
    if (t < 768) {
        const int g = t >> 8;
        const int i = (t >> 4) & 15;
        const int j = t & 15;
        float gr = 0.f, gi = 0.f;
#pragma unroll
        for (int k = 0; k < 16; ++k) {
            const float vv = sV[i * 16 + k] * sV[j * 16 + k];
            gr = fmaf(vv,  sC[(g << 4) + k], gr);
            gi = fmaf(vv, -sS[(g << 4) + k], gi);
        }
        sG[g][i][j] = make_float2(gr, gi);
    }

    // scatter state into padded interleaved LDS layout
    const int e0 = t << 2;
    const int sbase = (e0 >> 8) * S0 + ((e0 >> 4) & 15) * S1 + (e0 & 15);
    st[sbase + 0] = make_float2(re4.x, im4.x);
    st[sbase + 1] = make_float2(re4.y, im4.y);
    st[sbase + 2] = make_float2(re4.z, im4.z);
    st[sbase + 3] = make_float2(re4.w, im4.w);
    __syncthreads();

    // thread decomposition: fg = fiber group (128), r0 = row pair (8)
    const int fg = t & 127;
    const int r0 = (t >> 7) << 1;

    // In-place contraction pass. Thread: fibers {fg, fg+128}, rows {r0, r0+1}.
    // Gate rows in registers (wave-uniform broadcast). All reads precede the
    // barrier; writes after => in-place safe. Load+FMA fused: 1 float2 live.
    auto pass = [&](const float2 (*__restrict__ G)[16],
                    const int BH, const int BK, const int STRIDE) {
        float2 g0[16], g1[16];
#pragma unroll
        for (int j = 0; j < 16; ++j) {
            g0[j] = G[r0][j];
            g1[j] = G[r0 + 1][j];
        }
        float2 y[2][2];
#pragma unroll
        for (int fl = 0; fl < 2; ++fl) {
            const int f = fg + (fl << 7);
            const int base = (f >> 4) * BH + (f & 15) * BK;
            float ar0 = 0.f, ai0 = 0.f, ar1 = 0.f, ai1 = 0.f;
#pragma unroll
            for (int j = 0; j < 16; ++j) {
                const float2 x = st[base + j * STRIDE];
                ar0 = fmaf(g0[j].x,  x.x, ar0);
                ar0 = fmaf(-g0[j].y, x.y, ar0);
                ai0 = fmaf(g0[j].x,  x.y, ai0);
                ai0 = fmaf(g0[j].y,  x.x, ai0);
                ar1 = fmaf(g1[j].x,  x.x, ar1);
                ar1 = fmaf(-g1[j].y, x.y, ar1);
                ai1 = fmaf(g1[j].x,  x.y, ai1);
                ai1 = fmaf(g1[j].y,  x.x, ai1);
            }
            y[fl][0] = make_float2(ar0, ai0);
            y[fl][1] = make_float2(ar1, ai1);
        }
        __syncthreads();
#pragma unroll
        for (int fl = 0; fl < 2; ++fl) {
            const int f = fg + (fl << 7);
            const int base = (f >> 4) * BH + (f & 15) * BK;
            st[base + r0 * STRIDE]       = y[fl][0];
            st[base + (r0 + 1) * STRIDE] = y[fl][1];
        }
        __syncthreads();
    };

    // U2: fibers (i0,i1), stride 1.   U1: fibers (i0,i2), stride S1.
    pass(sG[2], S0, S1, 1);
    pass(sG[1], S0, 1, S1);

    // Final pass U0 (fibers (i1,i2), stride S0): write straight to global,
    // no LDS write-back, no barriers. Element e = i0*256 + i1*16 + i2 = i0*256 + f
    // => lane-consecutive stores (fully coalesced).
    {
        float2 g0[16], g1[16];
#pragma unroll
        for (int j = 0; j < 16; ++j) {
            g0[j] = sG[0][r0][j];
            g1[j] = sG[0][r0 + 1][j];
        }
        float* __restrict__ ore = out + (size_t)b * DIM;
        float* __restrict__ oim = out + (size_t)BATCH * DIM + (size_t)b * DIM;
#pragma unroll
        for (int fl = 0; fl < 2; ++fl) {
            const int f = fg + (fl << 7);
            const int base = (f >> 4) * S1 + (f & 15);
            float ar0 = 0.f, ai0 = 0.f, ar1 = 0.f, ai1 = 0.f;
#pragma unroll
            for (int j = 0; j < 16; ++j) {
                const float2 x = st[base + j * S0];
                ar0 = fmaf(g0[j].x,  x.x, ar0);
                ar0 = fmaf(-g0[j].y, x.y, ar0);
                ai0 = fmaf(g0[j].x,  x.y, ai0);
                ai0 = fmaf(g0[j].y,  x.x, ai0);
                ar1 = fmaf(g1[j].x,  x.x, ar1);
                ar1 = fmaf(-g1[j].y, x.y, ar1);
                ai1 = fmaf(g1[j].x,  x.y, ai1);
                ai1 = fmaf(g1[j].y,  x.x, ai1);
            }
            ore[r0 * 256 + f]       = ar0;
            oim[r0 * 256 + f]       = ai0;
            ore[(r0 + 1) * 256 + f] = ar1;
            oim[(r0 + 1) * 256 + f] = ai1;
        }
    }
}

extern "C" void kernel_launch(void* const* d_in, const int* in_sizes, int n_in,
                              void* d_out, int out_size, void* d_ws, size_t ws_size,
                              hipStream_t stream) {
    const float* thetas = (const float*)d_in[0];
    const float* evecs  = (const float*)d_in[1];
    const float* evals  = (const float*)d_in[2];
    const float* sre    = (const float*)d_in[3];
    const float* sim    = (const float*)d_in[4];
    float* out = (float*)d_out;
    ulayer_kernel<<<BATCH, NT, 0, stream>>>(thetas, evecs, evals, sre, sim, out);
}